// Round 3
// baseline (711.390 us; speedup 1.0000x reference)
//
#include <hip/hip_runtime.h>
#include <math.h>

#define NFEAT 22
#define ROWS_PER_THREAD 2
#define BLOCK 256
#define REPEAT 40   // DIAGNOSTIC ONLY: force this dispatch into rocprof top-5
                    // (harness poison-fills run 320 us; our kernel at 26 us is
                    // otherwise invisible). FETCH_SIZE/40 = per-pass bytes ->
                    // resolves 64B vs 128B fetch granularity question.
                    // Output is rewritten identically each pass: deterministic.

// Reference quirk replicated exactly: start_i is NEVER incremented in the
// Python reference, so every node i computes relu(x[:, 0:fn_i] @ kernels[off..] + b_i).
// Only x columns 0..12 are ever read (max feature = 13).

__global__ __launch_bounds__(BLOCK, 8) void hnn_fused_kernel(
    const float* x,                      // no __restrict__: keep reloads honest vs memory clobber
    const float* __restrict__ kernels,
    const float* __restrict__ biases,
    const float* __restrict__ final_kernel,
    const float* __restrict__ final_bias,
    float* __restrict__ out,
    int batch)
{
    constexpr int FN[NFEAT] = {10,13,13,7,3,6,3,13,5,4,6,4,5,4,4,5,4,3,3,7,3,3};

    const int base = blockIdx.x * (BLOCK * ROWS_PER_THREAD) + threadIdx.x;

    for (int rep = 0; rep < REPEAT; ++rep) {
        // Memory clobber: forbids hoisting the x loads / sinking the store
        // out of the rep loop. Each pass re-reads x and re-stores out.
        asm volatile("" ::: "memory");

        #pragma unroll
        for (int r = 0; r < ROWS_PER_THREAD; ++r) {
            const int row = base + r * BLOCK;
            if (row >= batch) continue;

            const size_t rb = (size_t)row * 128;
            const float4* xr = reinterpret_cast<const float4*>(x + rb);

            // Identical access pattern to R2: 3 x float4 (bytes 0..47) + 1 dword (48..51).
            float4 a = xr[0];
            float4 b = xr[1];
            float4 c = xr[2];
            float xv[13] = {a.x, a.y, a.z, a.w,
                            b.x, b.y, b.z, b.w,
                            c.x, c.y, c.z, c.w,
                            x[rb + 12]};

            float z = final_bias[0];
            int off = 0;
            #pragma unroll
            for (int i = 0; i < NFEAT; ++i) {
                float acc = biases[i];
                #pragma unroll
                for (int j = 0; j < FN[i]; ++j) {
                    acc = fmaf(xv[j], kernels[off + j], acc);
                }
                off += FN[i];
                z = fmaf(fmaxf(acc, 0.0f), final_kernel[i], z);
            }

            out[row] = 1.0f / (1.0f + __expf(-z));
        }
    }
}

extern "C" void kernel_launch(void* const* d_in, const int* in_sizes, int n_in,
                              void* d_out, int out_size, void* d_ws, size_t ws_size,
                              hipStream_t stream)
{
    const float* x            = (const float*)d_in[0];
    const float* kernels      = (const float*)d_in[1];
    const float* biases       = (const float*)d_in[2];
    const float* final_kernel = (const float*)d_in[3];
    const float* final_bias   = (const float*)d_in[4];
    float* out = (float*)d_out;

    const int batch = out_size;  // 1048576
    const int rows_per_block = BLOCK * ROWS_PER_THREAD;
    const int grid = (batch + rows_per_block - 1) / rows_per_block;

    hnn_fused_kernel<<<grid, BLOCK, 0, stream>>>(
        x, kernels, biases, final_kernel, final_bias, out, batch);
}

// Round 4
// 31.199 us; speedup vs baseline: 22.8014x; 22.8014x over previous
//
#include <hip/hip_runtime.h>
#include <math.h>

#define NFEAT 22
#define BLOCK 256
#define ROWS_PER_BLOCK 256   // 1 row per thread in compute phase

// Reference quirk replicated exactly: start_i is NEVER incremented in the
// Python reference, so every node i computes relu(x[:, 0:fn_i] @ kernels[off..] + b_i).
// Only x columns 0..12 are ever read (max feature = 13); they live in the
// first 64-B sector of each 512-B row. R3 diagnostic measured fetch = 64 B/row
// (minimal), steady-state 3.57 TB/s, zero conflicts.
//
// R4 change: cooperative coalesced staging. 4 lanes load one row's 64-B
// sector (one float4 each, consecutive addresses) -> each wave-level load
// covers 16 full cache lines, 1 L1->L2 request per line (was 4 requests/line
// from 4 uncoalesced instructions). LDS-staged, XOR-swizzled (chunk ^=
// (row>>1)&3) -> conflict-free b128 writes AND reads (8 bank-passes, the
// 1KB/128B minimum). Compute phase unchanged: thread-per-row, unrolled FMA
// chain, uniform weights via s_loads.

__global__ __launch_bounds__(BLOCK, 8) void hnn_fused_kernel(
    const float* __restrict__ x,
    const float* __restrict__ kernels,
    const float* __restrict__ biases,
    const float* __restrict__ final_kernel,
    const float* __restrict__ final_bias,
    float* __restrict__ out,
    int batch)
{
    constexpr int FN[NFEAT] = {10,13,13,7,3,6,3,13,5,4,6,4,5,4,4,5,4,3,3,7,3,3};

    __shared__ float lds[ROWS_PER_BLOCK * 16];   // 256 rows x 64 B = 16 KB

    const int t = threadIdx.x;
    const int rowBase = blockIdx.x * ROWS_PER_BLOCK;

    // ---- Stage: 4 lanes per row, one float4 (16 B) each ----
    {
        const int c    = t & 3;        // 16-B chunk within the row's 64-B sector
        const int rloc = t >> 2;       // local row 0..63 (+64k below)
        const int swz  = (t >> 3) & 3; // == ((rloc+64k)>>1)&3 for all k
        const int ce   = c ^ swz;      // swizzled chunk slot
        #pragma unroll
        for (int k = 0; k < 4; ++k) {
            const int rr    = rloc + 64 * k;          // local row 0..255
            const int row_g = rowBase + rr;
            if (row_g < batch) {
                const float4 v = *reinterpret_cast<const float4*>(
                    x + (size_t)row_g * 128 + c * 4);
                *reinterpret_cast<float4*>(&lds[rr * 16 + ce * 4]) = v;
            }
        }
    }
    __syncthreads();

    // ---- Compute: thread t owns row rowBase + t ----
    const int row = rowBase + t;
    if (row >= batch) return;

    const int rs = (t >> 1) & 3;       // read-side swizzle key for row t
    float4 q[4];
    #pragma unroll
    for (int cc = 0; cc < 4; ++cc) {
        const int ce = cc ^ rs;
        q[cc] = *reinterpret_cast<const float4*>(&lds[t * 16 + ce * 4]);
    }
    const float xv[13] = {q[0].x, q[0].y, q[0].z, q[0].w,
                          q[1].x, q[1].y, q[1].z, q[1].w,
                          q[2].x, q[2].y, q[2].z, q[2].w,
                          q[3].x};

    float z = final_bias[0];
    int off = 0;
    #pragma unroll
    for (int i = 0; i < NFEAT; ++i) {
        float acc = biases[i];
        #pragma unroll
        for (int j = 0; j < FN[i]; ++j) {
            acc = fmaf(xv[j], kernels[off + j], acc);   // uniform -> s_load, ~free
        }
        off += FN[i];
        z = fmaf(fmaxf(acc, 0.0f), final_kernel[i], z);
    }

    out[row] = 1.0f / (1.0f + __expf(-z));
}

extern "C" void kernel_launch(void* const* d_in, const int* in_sizes, int n_in,
                              void* d_out, int out_size, void* d_ws, size_t ws_size,
                              hipStream_t stream)
{
    const float* x            = (const float*)d_in[0];
    const float* kernels      = (const float*)d_in[1];
    const float* biases       = (const float*)d_in[2];
    const float* final_kernel = (const float*)d_in[3];
    const float* final_bias   = (const float*)d_in[4];
    float* out = (float*)d_out;

    const int batch = out_size;  // 1048576
    const int grid = (batch + ROWS_PER_BLOCK - 1) / ROWS_PER_BLOCK;  // 4096

    hnn_fused_kernel<<<grid, BLOCK, 0, stream>>>(
        x, kernels, biases, final_kernel, final_bias, out, batch);
}